// Round 7
// baseline (121.461 us; speedup 1.0000x reference)
//
#include <hip/hip_runtime.h>

#define NSTATE 128
#define NM1    127
#define UDIM   4

typedef float v2f __attribute__((ext_vector_type(2)));

// R7: bucket-by-state restructure.
//   K1 histogram (LDS-aggregated) -> K2 scan (128 bins) -> K3 scatter
//   (block-reserved, within-block LDS ranking) -> K4 compute: each wave pinned
//   to one state s, W[s]-fragments loaded ONCE into registers, rows streamed.
// Per-row global reads drop from ~2.5KB (whole W[s] row re-gathered per row)
// to 20B (idx + u). Output identical per-row regardless of scatter order.
// No-max softmax validated R2-R6 (absmax 0.0625 vs thr 0.186).
//
// ws layout (bytes): [0,512) hist, [512,1024) base, [1024,1536) cursor,
//                    [2048, 2048+4T) idx.

__device__ __forceinline__ float dot4(const float4 a, const float4 b) {
    return fmaf(a.x, b.x, fmaf(a.y, b.y, fmaf(a.z, b.z, a.w * b.w)));
}

// ---------------- K1: histogram ----------------
__global__ __launch_bounds__(256) void k_hist(
    const int* __restrict__ x, int T, unsigned* __restrict__ hist)
{
    __shared__ unsigned h[NSTATE];
    for (int i = threadIdx.x; i < NSTATE; i += blockDim.x) h[i] = 0;
    __syncthreads();
    for (int t = blockIdx.x * blockDim.x + threadIdx.x; t < T;
         t += gridDim.x * blockDim.x)
        atomicAdd(&h[x[t]], 1u);
    __syncthreads();
    for (int i = threadIdx.x; i < NSTATE; i += blockDim.x)
        if (h[i]) atomicAdd(&hist[i], h[i]);
}

// ---------------- K2: exclusive scan over 128 bins ----------------
__global__ __launch_bounds__(128) void k_scan(
    const unsigned* __restrict__ hist, unsigned* __restrict__ base,
    unsigned* __restrict__ cursor)
{
    __shared__ unsigned a[NSTATE], b[NSTATE];
    const int i = threadIdx.x;
    a[i] = hist[i];
    __syncthreads();
    unsigned* src = a; unsigned* dst = b;
    #pragma unroll
    for (int off = 1; off < NSTATE; off <<= 1) {
        dst[i] = (i >= off) ? (src[i] + src[i - off]) : src[i];
        __syncthreads();
        unsigned* tmp = src; src = dst; dst = tmp;
    }
    const unsigned excl = src[i] - hist[i];
    base[i] = excl;
    cursor[i] = excl;
}

// ---------------- K3: scatter with block reservation ----------------
__global__ __launch_bounds__(256) void k_scatter(
    const int* __restrict__ x, int T, unsigned* __restrict__ cursor,
    unsigned* __restrict__ idx)
{
    __shared__ unsigned h[NSTATE], lbase[NSTATE], lofs[NSTATE];
    const int tid = threadIdx.x;
    if (tid < NSTATE) { h[tid] = 0; lofs[tid] = 0; }
    __syncthreads();
    const int t = blockIdx.x * 256 + tid;
    int s = -1;
    if (t < T) { s = x[t]; atomicAdd(&h[s], 1u); }
    __syncthreads();
    if (tid < NSTATE && h[tid]) lbase[tid] = atomicAdd(&cursor[tid], h[tid]);
    __syncthreads();
    if (t < T) {
        const unsigned r = atomicAdd(&lofs[s], 1u);
        idx[lbase[s] + r] = (unsigned)t;
    }
}

// ---------------- K4: compute, wave pinned to state ----------------
__global__ __launch_bounds__(256) void k_compute(
    const unsigned* __restrict__ base, const unsigned* __restrict__ hist,
    const unsigned* __restrict__ idx,
    const float* __restrict__ u_curr, const float* __restrict__ logP0,
    const float* __restrict__ W, float* __restrict__ out)
{
    const int lane  = threadIdx.x & 63;
    const int wave  = (blockIdx.x * blockDim.x + threadIdx.x) >> 6;
    const int s     = wave & (NSTATE - 1);
    const int chunk = wave >> 7;                // 0..63: 64 waves share a bucket
    const unsigned b = base[s];
    const unsigned n = hist[s];
    const int j0 = 2 * lane, j1 = j0 + 1;

    // per-state operands, loaded ONCE
    const int  k0 = (j0 != s) ? (j0 - (j0 > s)) : 0;
    const int  k1 = (j1 != s) ? (j1 - (j1 > s)) : 0;
    const float4 w0 = *reinterpret_cast<const float4*>(W + ((size_t)s * NM1 + k0) * UDIM);
    const float4 w1 = *reinterpret_cast<const float4*>(W + ((size_t)s * NM1 + k1) * UDIM);
    const float2 lp = *reinterpret_cast<const float2*>(logP0 + (size_t)s * NSTATE + j0);
    const bool p0 = (j0 != s), p1 = (j1 != s);

    unsigned i = chunk;
    if (i >= n) return;

    int t = (int)idx[b + i];
    t = __builtin_amdgcn_readfirstlane(t);
    float4 u = *reinterpret_cast<const float4*>(u_curr + (size_t)t * UDIM);

    while (true) {
        // prefetch next row's idx+u before this row's store
        const unsigned inext = i + 64;
        const bool has_next = (inext < n);
        int tn = t; float4 un = u;
        if (has_next) {
            tn = (int)idx[b + inext];
            tn = __builtin_amdgcn_readfirstlane(tn);
            un = *reinterpret_cast<const float4*>(u_curr + (size_t)tn * UDIM);
        }

        const float st0 = p0 ? dot4(u, w0) : 0.0f;
        const float st1 = p1 ? dot4(u, w1) : 0.0f;
        const float v0 = lp.x + st0, v1 = lp.y + st1;

        float e = __expf(v0) + __expf(v1);
        #pragma unroll
        for (int off = 32; off >= 1; off >>= 1)
            e += __shfl_xor(e, off, 64);
        const float l = __logf(e);

        v2f o; o[0] = v0 - l; o[1] = v1 - l;
        __builtin_nontemporal_store(o, reinterpret_cast<v2f*>(out + (size_t)t * NSTATE + j0));

        if (!has_next) break;
        i = inext; t = tn; u = un;
    }
}

// ---------------- fallback (R6-style single kernel) if ws too small ----------------
__global__ __launch_bounds__(256) void k_fallback(
    const int* __restrict__ x_curr, const float* __restrict__ u_curr,
    const float* __restrict__ logP0, const float* __restrict__ W,
    float* __restrict__ out, int T)
{
    const int lane    = threadIdx.x & 63;
    const int wave_id = (blockIdx.x * blockDim.x + threadIdx.x) >> 6;
    const int nwaves  = (gridDim.x * blockDim.x) >> 6;
    const int j0 = 2 * lane, j1 = j0 + 1;
    for (int t = wave_id; t < T; t += nwaves) {
        int s = x_curr[t];
        s = __builtin_amdgcn_readfirstlane(s);
        const float4 u = *reinterpret_cast<const float4*>(u_curr + (size_t)t * UDIM);
        float st0 = 0.0f, st1 = 0.0f;
        if (j0 != s) {
            const int k = j0 - (j0 > s);
            const float4 w = *reinterpret_cast<const float4*>(W + ((size_t)s * NM1 + k) * UDIM);
            st0 = dot4(u, w);
        }
        if (j1 != s) {
            const int k = j1 - (j1 > s);
            const float4 w = *reinterpret_cast<const float4*>(W + ((size_t)s * NM1 + k) * UDIM);
            st1 = dot4(u, w);
        }
        const float2 lp = *reinterpret_cast<const float2*>(logP0 + (size_t)s * NSTATE + j0);
        const float v0 = lp.x + st0, v1 = lp.y + st1;
        float e = __expf(v0) + __expf(v1);
        #pragma unroll
        for (int off = 32; off >= 1; off >>= 1)
            e += __shfl_xor(e, off, 64);
        const float l = __logf(e);
        v2f o; o[0] = v0 - l; o[1] = v1 - l;
        __builtin_nontemporal_store(o, reinterpret_cast<v2f*>(out + (size_t)t * NSTATE + j0));
    }
}

extern "C" void kernel_launch(void* const* d_in, const int* in_sizes, int n_in,
                              void* d_out, int out_size, void* d_ws, size_t ws_size,
                              hipStream_t stream) {
    const int*   x_curr = (const int*)  d_in[0];
    const float* u_curr = (const float*)d_in[1];
    const float* logP0  = (const float*)d_in[2];
    const float* W      = (const float*)d_in[3];
    float*       out    = (float*)d_out;

    const int T = in_sizes[0];
    const size_t need = 2048 + (size_t)T * 4;

    if (ws_size < need) {
        dim3 grid(2048), block(256);
        hipLaunchKernelGGL(k_fallback, grid, block, 0, stream,
                           x_curr, u_curr, logP0, W, out, T);
        return;
    }

    unsigned* hist   = (unsigned*)d_ws;                    // 128
    unsigned* basep  = (unsigned*)((char*)d_ws + 512);     // 128
    unsigned* cursor = (unsigned*)((char*)d_ws + 1024);    // 128
    unsigned* idx    = (unsigned*)((char*)d_ws + 2048);    // T

    hipMemsetAsync(hist, 0, NSTATE * sizeof(unsigned), stream);
    hipLaunchKernelGGL(k_hist,    dim3(512),  dim3(256), 0, stream, x_curr, T, hist);
    hipLaunchKernelGGL(k_scan,    dim3(1),    dim3(128), 0, stream, hist, basep, cursor);
    hipLaunchKernelGGL(k_scatter, dim3((T + 255) / 256), dim3(256), 0, stream,
                       x_curr, T, cursor, idx);
    hipLaunchKernelGGL(k_compute, dim3(2048), dim3(256), 0, stream,
                       basep, hist, idx, u_curr, logP0, W, out);
}

// Round 8
// 95.719 us; speedup vs baseline: 1.2689x; 1.2689x over previous
//
#include <hip/hip_runtime.h>

#define NSTATE 128
#define NM1    127
#define UDIM   4

typedef float v2f __attribute__((ext_vector_type(2)));

// R8: de-interleaved padded weight table.
// Pre-pass builds Wt[parity][s][lane] (float4, 256KB in d_ws):
//   Wt[p][s][l] = (j==s) ? 0 : W[s][j-(j>s)],  j = 2l+p.
// Hot kernel: lane l's two W loads are base + 16*l contiguous (full-line TA
// utilization, 16 lines/instr instead of 32), self-column predicate gone
// (zero vec makes stim 0 automatically). Otherwise identical to R6:
// one wave/row, uniform s, no-max softmax (validated R2-R7), pinned
// 2-row-group pipeline, nt stores last.

__device__ __forceinline__ float dot4(const float4 a, const float4 b) {
    return fmaf(a.x, b.x, fmaf(a.y, b.y, fmaf(a.z, b.z, a.w * b.w)));
}

// ---------------- pre-pass: build Wt ----------------
__global__ __launch_bounds__(128) void k_build_wt(
    const float* __restrict__ W, float4* __restrict__ Wt)
{
    const int s = blockIdx.x;      // 0..127
    const int j = threadIdx.x;     // 0..127
    float4 v = make_float4(0.0f, 0.0f, 0.0f, 0.0f);
    if (j != s) {
        const int k = j - (j > s);
        v = *reinterpret_cast<const float4*>(W + ((size_t)s * NM1 + k) * UDIM);
    }
    Wt[(((j & 1) * NSTATE + s) << 6) + (j >> 1)] = v;
}

// ---------------- hot kernel ----------------
__global__ __launch_bounds__(256) void llm_markov_kernel(
    const int*    __restrict__ x_curr,
    const float*  __restrict__ u_curr,
    const float*  __restrict__ logP0,
    const float4* __restrict__ Wt,
    float*        __restrict__ out,
    int T)
{
    const int lane    = threadIdx.x & 63;
    const int wave_id = (blockIdx.x * blockDim.x + threadIdx.x) >> 6;
    const int S       = (gridDim.x * blockDim.x) >> 6;  // row stride
    const int G       = 2 * S;                          // group stride (2 rows)
    const int j0      = 2 * lane;

    if (wave_id >= T) return;

    auto clampT = [&](int t) { return t < T ? t : T - 1; };

    int tA = wave_id;

    // ---------------- prologue ----------------
    int a0 = clampT(tA), a1 = clampT(tA + S);
    int xA0 = x_curr[a0], xA1 = x_curr[a1];
    float4 uA0 = *reinterpret_cast<const float4*>(u_curr + (size_t)a0 * UDIM);
    float4 uA1 = *reinterpret_cast<const float4*>(u_curr + (size_t)a1 * UDIM);
    int b0 = clampT(tA + G), b1 = clampT(tA + G + S);
    int xB0 = x_curr[b0], xB1 = x_curr[b1];
    float4 uB0 = *reinterpret_cast<const float4*>(u_curr + (size_t)b0 * UDIM);
    float4 uB1 = *reinterpret_cast<const float4*>(u_curr + (size_t)b1 * UDIM);

    int sA0 = __builtin_amdgcn_readfirstlane(xA0);
    int sA1 = __builtin_amdgcn_readfirstlane(xA1);

    float4 wA00 = Wt[(sA0 << 6) + lane];
    float4 wA01 = Wt[((NSTATE + sA0) << 6) + lane];
    float4 wA10 = Wt[(sA1 << 6) + lane];
    float4 wA11 = Wt[((NSTATE + sA1) << 6) + lane];
    float2 lpA0 = *reinterpret_cast<const float2*>(logP0 + (size_t)sA0 * NSTATE + j0);
    float2 lpA1 = *reinterpret_cast<const float2*>(logP0 + (size_t)sA1 * NSTATE + j0);

    // ---------------- main pipelined loop ----------------
    while (tA + S < T) {
        // phase 1: prefetch x/u for group C = A+2G
        const int c0 = clampT(tA + 2 * G), c1 = clampT(tA + 2 * G + S);
        int   xC0 = x_curr[c0], xC1 = x_curr[c1];
        float4 uC0 = *reinterpret_cast<const float4*>(u_curr + (size_t)c0 * UDIM);
        float4 uC1 = *reinterpret_cast<const float4*>(u_curr + (size_t)c1 * UDIM);
        __builtin_amdgcn_sched_barrier(0);

        // phase 2: resolve group B state ids + issue Wt/lp loads for B
        const int sB0 = __builtin_amdgcn_readfirstlane(xB0);
        const int sB1 = __builtin_amdgcn_readfirstlane(xB1);
        float4 wB00 = Wt[(sB0 << 6) + lane];
        float4 wB01 = Wt[((NSTATE + sB0) << 6) + lane];
        float4 wB10 = Wt[(sB1 << 6) + lane];
        float4 wB11 = Wt[((NSTATE + sB1) << 6) + lane];
        float2 lpB0 = *reinterpret_cast<const float2*>(logP0 + (size_t)sB0 * NSTATE + j0);
        float2 lpB1 = *reinterpret_cast<const float2*>(logP0 + (size_t)sB1 * NSTATE + j0);
        __builtin_amdgcn_sched_barrier(0);

        // phase 3: compute group A (operands loaded a full iteration ago)
        const float v00 = lpA0.x + dot4(uA0, wA00);
        const float v01 = lpA0.y + dot4(uA0, wA01);
        const float v10 = lpA1.x + dot4(uA1, wA10);
        const float v11 = lpA1.y + dot4(uA1, wA11);

        float e0 = __expf(v00) + __expf(v01);
        float e1 = __expf(v10) + __expf(v11);
        #pragma unroll
        for (int off = 32; off >= 1; off >>= 1) {
            e0 += __shfl_xor(e0, off, 64);
            e1 += __shfl_xor(e1, off, 64);
        }
        const float l0 = __logf(e0);
        const float l1 = __logf(e1);
        __builtin_amdgcn_sched_barrier(0);

        // phase 4: stores for group A (issued LAST)
        v2f o0, o1;
        o0[0] = v00 - l0; o0[1] = v01 - l0;
        o1[0] = v10 - l1; o1[1] = v11 - l1;
        __builtin_nontemporal_store(o0, reinterpret_cast<v2f*>(out + (size_t)tA * NSTATE + j0));
        __builtin_nontemporal_store(o1, reinterpret_cast<v2f*>(out + (size_t)(tA + S) * NSTATE + j0));
        __builtin_amdgcn_sched_barrier(0);

        // rotate pipeline registers
        tA += G;
        sA0 = sB0; sA1 = sB1;
        uA0 = uB0; uA1 = uB1;
        wA00 = wB00; wA01 = wB01; wA10 = wB10; wA11 = wB11;
        lpA0 = lpB0; lpA1 = lpB1;
        xB0 = xC0; xB1 = xC1;
        uB0 = uC0; uB1 = uC1;
    }

    // ---------------- tail: at most one row (operands resident) ----------------
    if (tA < T) {
        const float v0 = lpA0.x + dot4(uA0, wA00);
        const float v1 = lpA0.y + dot4(uA0, wA01);
        float e = __expf(v0) + __expf(v1);
        #pragma unroll
        for (int off = 32; off >= 1; off >>= 1)
            e += __shfl_xor(e, off, 64);
        const float l = __logf(e);
        v2f o;
        o[0] = v0 - l; o[1] = v1 - l;
        __builtin_nontemporal_store(o, reinterpret_cast<v2f*>(out + (size_t)tA * NSTATE + j0));
    }
}

// ---------------- fallback (no ws): R1-style direct kernel ----------------
__global__ __launch_bounds__(256) void k_fallback(
    const int* __restrict__ x_curr, const float* __restrict__ u_curr,
    const float* __restrict__ logP0, const float* __restrict__ W,
    float* __restrict__ out, int T)
{
    const int lane    = threadIdx.x & 63;
    const int wave_id = (blockIdx.x * blockDim.x + threadIdx.x) >> 6;
    const int nwaves  = (gridDim.x * blockDim.x) >> 6;
    const int j0 = 2 * lane, j1 = j0 + 1;
    for (int t = wave_id; t < T; t += nwaves) {
        int s = x_curr[t];
        s = __builtin_amdgcn_readfirstlane(s);
        const float4 u = *reinterpret_cast<const float4*>(u_curr + (size_t)t * UDIM);
        float st0 = 0.0f, st1 = 0.0f;
        if (j0 != s) {
            const int k = j0 - (j0 > s);
            const float4 w = *reinterpret_cast<const float4*>(W + ((size_t)s * NM1 + k) * UDIM);
            st0 = dot4(u, w);
        }
        if (j1 != s) {
            const int k = j1 - (j1 > s);
            const float4 w = *reinterpret_cast<const float4*>(W + ((size_t)s * NM1 + k) * UDIM);
            st1 = dot4(u, w);
        }
        const float2 lp = *reinterpret_cast<const float2*>(logP0 + (size_t)s * NSTATE + j0);
        const float v0 = lp.x + st0, v1 = lp.y + st1;
        float e = __expf(v0) + __expf(v1);
        #pragma unroll
        for (int off = 32; off >= 1; off >>= 1)
            e += __shfl_xor(e, off, 64);
        const float l = __logf(e);
        v2f o; o[0] = v0 - l; o[1] = v1 - l;
        __builtin_nontemporal_store(o, reinterpret_cast<v2f*>(out + (size_t)t * NSTATE + j0));
    }
}

extern "C" void kernel_launch(void* const* d_in, const int* in_sizes, int n_in,
                              void* d_out, int out_size, void* d_ws, size_t ws_size,
                              hipStream_t stream) {
    const int*   x_curr = (const int*)  d_in[0];
    const float* u_curr = (const float*)d_in[1];
    const float* logP0  = (const float*)d_in[2];
    const float* W      = (const float*)d_in[3];
    float*       out    = (float*)d_out;

    const int T = in_sizes[0];
    const size_t need = (size_t)2 * NSTATE * 64 * sizeof(float4);  // 256 KB

    if (ws_size < need) {
        dim3 grid(2048), block(256);
        hipLaunchKernelGGL(k_fallback, grid, block, 0, stream,
                           x_curr, u_curr, logP0, W, out, T);
        return;
    }

    float4* Wt = (float4*)d_ws;

    hipLaunchKernelGGL(k_build_wt, dim3(NSTATE), dim3(NSTATE), 0, stream, W, Wt);
    hipLaunchKernelGGL(llm_markov_kernel, dim3(2048), dim3(256), 0, stream,
                       x_curr, u_curr, logP0, Wt, out, T);
}